// Round 11
// baseline (295.437 us; speedup 1.0000x reference)
//
#include <hip/hip_runtime.h>
#include <hip/hip_bf16.h>
#include <hip/hip_cooperative_groups.h>
#include <stdint.h>

namespace cg = cooperative_groups;

#define B_ 16
#define Q_ 1800
#define C_ 256
#define WPR 29            // u64 words per adjacency row = ceil(1800/64)
#define QPAD 1856         // padded compacted-row capacity
#define TBK 15            // 128-wide tiles per dim: 15*128 = 1920 >= QPAD
#define NTRI 120          // triangular tile count = TBK*(TBK+1)/2
#define OUT_SIG_ELEMS (B_*Q_*C_)

typedef unsigned long long u64;
typedef unsigned int u32;
typedef __attribute__((ext_vector_type(8))) short bf16x8;   // 8 bf16 (4 VGPRs)
typedef __attribute__((ext_vector_type(4))) float f32x4;    // 4 fp32 acc

// ============================================================================
// Fused cooperative kernel: 5 phases split by grid.sync() (device-scope fence
// gives cross-XCD visibility). Static LDS exactly 64KB -> 2 blocks/CU.
// Phase bodies are ports of the round-9 verified kernels.
// ============================================================================
__global__ __launch_bounds__(256, 2)
void k_fused(const float* __restrict__ sig, const float* __restrict__ logits,
             float* __restrict__ out_sig, float* __restrict__ out_mask,
             float* __restrict__ out_scores,
             float* __restrict__ scores, int* __restrict__ sel_idx,
             int* __restrict__ best_idx, float* __restrict__ best_sc,
             int* __restrict__ sel_cnt, int* __restrict__ nroots,
             u64* __restrict__ adj, unsigned short* __restrict__ nsig,
             u32* __restrict__ rowmin)
{
  cg::grid_group grid = cg::this_grid();
  const int bid = blockIdx.x;
  const int t = threadIdx.x;
  const int lane = t & 63, wid = t >> 6;

  __shared__ char smem[65536] __attribute__((aligned(16)));  // phase union, 64KB

  // ================= Phase 1: sigmoid + select + fallback + compact ========
  if (bid < B_) {
    int* wsum = reinterpret_cast<int*>(smem);           // [4]
    u64* kw   = reinterpret_cast<u64*>(smem + 16);      // [4]
    int* stot = reinterpret_cast<int*>(smem + 48);
    const int b = bid;
    const float* lgb = logits + b * Q_;
    float* scb = scores + b * Q_;

    int f[8]; int cnt = 0; u64 mk = 0;
    #pragma unroll
    for (int e = 0; e < 8; ++e) {
      int q = t * 8 + e;
      int fl = 0;
      if (q < Q_) {
        float sc = 1.0f / (1.0f + expf(-lgb[q]));
        scb[q] = sc;
        fl = (sc >= 0.5f) ? 1 : 0;
        u64 key = ((u64)__float_as_uint(sc) << 32) | (u32)(~(u32)q);
        mk = (mk > key) ? mk : key;
      }
      f[e] = fl; cnt += fl;
    }
    int incl = cnt;
    #pragma unroll
    for (int d = 1; d < 64; d <<= 1) {
      int v = __shfl_up(incl, d, 64);
      if (lane >= d) incl += v;
    }
    if (lane == 63) wsum[wid] = incl;
    __syncthreads();
    if (t == 0) {
      int acc = 0;
      #pragma unroll
      for (int i = 0; i < 4; ++i) { int v = wsum[i]; wsum[i] = acc; acc += v; }
      *stot = acc;
    }
    __syncthreads();
    int excl = wsum[wid] + incl - cnt;
    int total = *stot;

    if (total > 0) {
      #pragma unroll
      for (int e = 0; e < 8; ++e) {
        if (f[e]) { sel_idx[b * Q_ + excl] = t * 8 + e; excl++; }
      }
      if (t == 0) sel_cnt[b] = total;
    } else {                                // fallback: argmax-score query
      u64 r = mk;
      #pragma unroll
      for (int d = 1; d < 64; d <<= 1) {
        u64 o = __shfl_xor(r, d, 64);
        r = (o > r) ? o : r;
      }
      if (lane == 0) kw[wid] = r;
      __syncthreads();
      if (t == 0) {
        u64 m2 = kw[0];
        #pragma unroll
        for (int i = 1; i < 4; ++i) m2 = (kw[i] > m2) ? kw[i] : m2;
        sel_idx[b * Q_] = (int)(~(u32)m2);
        sel_cnt[b] = 1;
      }
    }
  }
  grid.sync();

  // ================= Phase 2: normalize selected rows -> bf16, rowmin init =
  for (int task = bid; task < B_ * (QPAD / 4); task += (int)gridDim.x) {
    int b = task / (QPAD / 4);
    int g = task - b * (QPAD / 4);
    int p = g * 4 + wid;
    int S = sel_cnt[b];
    int Spad = (S + 63) & ~63;
    if (p >= Spad) continue;
    if (lane == 0) rowmin[b * QPAD + p] = 0xFFFFFFFFu;
    unsigned short* dst = nsig + ((size_t)b * QPAD + p) * C_;
    if (p >= S) {                           // zero-pad row
      *reinterpret_cast<uint2*>(dst + lane * 4) = make_uint2(0u, 0u);
      continue;
    }
    int row = sel_idx[b * Q_ + p];
    const float* src = sig + ((size_t)b * Q_ + row) * C_;
    float4 v = *reinterpret_cast<const float4*>(src + lane * 4);
    float ss = v.x * v.x + v.y * v.y + v.z * v.z + v.w * v.w;
    #pragma unroll
    for (int m = 32; m; m >>= 1) ss += __shfl_xor(ss, m, 64);
    float inv = 1.0f / fmaxf(sqrtf(ss), 1e-12f);
    __hip_bfloat16 h0 = __float2bfloat16(v.x * inv);
    __hip_bfloat16 h1 = __float2bfloat16(v.y * inv);
    __hip_bfloat16 h2 = __float2bfloat16(v.z * inv);
    __hip_bfloat16 h3 = __float2bfloat16(v.w * inv);
    unsigned short u0, u1, u2, u3;
    __builtin_memcpy(&u0, &h0, 2); __builtin_memcpy(&u1, &h1, 2);
    __builtin_memcpy(&u2, &h2, 2); __builtin_memcpy(&u3, &h3, 2);
    uint2 wv2;
    wv2.x = (u32)u0 | ((u32)u1 << 16);
    wv2.y = (u32)u2 | ((u32)u3 << 16);
    *reinterpret_cast<uint2*>(dst + lane * 4) = wv2;
  }
  grid.sync();

  // ================= Phase 3: LDS-staged MFMA cosine-sim, triangular =======
  // batch = bid & 15 keeps the XCD pin (bid%8 == b%8); the 120 triangular
  // 128x128 tiles of each batch stride over its gridDim.x/16 blocks.
  {
    uint4* Alds = reinterpret_cast<uint4*>(smem);            // 32KB
    uint4* Blds = reinterpret_cast<uint4*>(smem + 32768);    // 32KB
    const int b = bid & 15;
    const int S = sel_cnt[b];
    const int wv = wid;
    const int lr = lane & 15, lg = lane >> 4;
    const char* gbase = (const char*)(nsig + (size_t)b * QPAD * C_);
    const int tstride = (int)(gridDim.x >> 4);

    for (int u0 = bid >> 4; u0 < NTRI; u0 += tstride) {
      int u = u0, tib = 0;
      while (u >= TBK - tib) { u -= TBK - tib; ++tib; }
      int tjb = tib + u;                    // tib <= tjb < TBK
      if (tjb * 128 >= S) continue;         // implies tib*128 < S (tib<=tjb)
      const bool diag = (tib == tjb);

      const int i1 = tib * 128 + (wv >> 1) * 64;
      const int j1 = tjb * 128 + (wv & 1) * 64;
      const bool live = (i1 < S) && (j1 < S);

      const char* arow = gbase + (size_t)tib * 128 * 512;
      const char* brow = gbase + (size_t)tjb * 128 * 512;

      f32x4 acc[4][4];
      #pragma unroll
      for (int rs = 0; rs < 4; ++rs)
        #pragma unroll
        for (int cg2 = 0; cg2 < 4; ++cg2) acc[rs][cg2] = (f32x4){0.f,0.f,0.f,0.f};

      const int ra0 = (wv >> 1) * 64;
      const int rb0 = (wv & 1) * 64;
      const char* Bbase = reinterpret_cast<const char*>(diag ? Alds : Blds);

      for (int kh = 0; kh < 2; ++kh) {
        #pragma unroll
        for (int it = 0; it < 8; ++it) {
          int o = it * 4096 + t * 16;       // linear byte offset in tile
          int r = o >> 8;
          int w = o & 255;
          int sw = o ^ ((r & 7) << 4);      // swizzled LDS byte offset
          uint4 va = *reinterpret_cast<const uint4*>(arow + (size_t)r * 512 + kh * 256 + w);
          Alds[sw >> 4] = va;
          if (!diag) {
            uint4 vb = *reinterpret_cast<const uint4*>(brow + (size_t)r * 512 + kh * 256 + w);
            Blds[sw >> 4] = vb;
          }
        }
        __syncthreads();
        if (live) {
          #pragma unroll
          for (int ks = 0; ks < 4; ++ks) {
            bf16x8 af[4], bf[4];
            #pragma unroll
            for (int rs = 0; rs < 4; ++rs) {
              int r = ra0 + rs * 16 + lr;
              int byte = r * 256 + ((ks * 64 + lg * 16) ^ ((r & 7) << 4));
              af[rs] = *reinterpret_cast<const bf16x8*>(
                  reinterpret_cast<const char*>(Alds) + byte);
            }
            #pragma unroll
            for (int cg2 = 0; cg2 < 4; ++cg2) {
              int r = rb0 + cg2 * 16 + lr;
              int byte = r * 256 + ((ks * 64 + lg * 16) ^ ((r & 7) << 4));
              bf[cg2] = *reinterpret_cast<const bf16x8*>(Bbase + byte);
            }
            #pragma unroll
            for (int rs = 0; rs < 4; ++rs)
              #pragma unroll
              for (int cg2 = 0; cg2 < 4; ++cg2)
                acc[rs][cg2] = __builtin_amdgcn_mfma_f32_16x16x32_bf16(
                    af[rs], bf[cg2], acc[rs][cg2], 0, 0, 0);
          }
        }
        __syncthreads();                    // all LDS reads done before reuse
      }

      // adjtile overlays Alds (safe: post-barrier, Alds no longer read)
      u64* adjt = reinterpret_cast<u64*>(smem);
      if (live) {
        adjt[wv * 64 + lane] = 0ull;        // wave-private strip, wave-ordered
        #pragma unroll
        for (int rs = 0; rs < 4; ++rs) {
          #pragma unroll
          for (int j = 0; j < 4; ++j) {
            u64 bits = 0ull;
            if (acc[rs][0][j] >= 0.8f) bits |= 1ull << (0  + lr);
            if (acc[rs][1][j] >= 0.8f) bits |= 1ull << (16 + lr);
            if (acc[rs][2][j] >= 0.8f) bits |= 1ull << (32 + lr);
            if (acc[rs][3][j] >= 0.8f) bits |= 1ull << (48 + lr);
            if (bits) atomicOr(&adjt[wv * 64 + rs * 16 + lg * 4 + j], bits);
          }
        }
        int gi = i1 + lane;
        u64 word = adjt[wv * 64 + lane];
        if (gi < S) {
          adj[((size_t)b * Q_ + gi) * WPR + (j1 >> 6)] = word;
          if (word) atomicMin(&rowmin[b * QPAD + gi], (u32)(j1 + __builtin_ctzll(word)));
        }
        if (!diag) {                        // mirrored word via bit-transpose
          u64 tw = 0ull;
          for (int i = 0; i < 64; ++i)
            tw |= ((adjt[wv * 64 + i] >> lane) & 1ull) << i;
          int gj = j1 + lane;
          if (gj < S) {
            adj[((size_t)b * Q_ + gj) * WPR + (i1 >> 6)] = tw;
            if (tw) atomicMin(&rowmin[b * QPAD + gj], (u32)(i1 + __builtin_ctzll(tw)));
          }
        }
      }
      __syncthreads();                      // before next tile's staging
    }
  }
  grid.sync();

  // ================= Phase 4: CC labels + best-per-component + compact =====
  if (bid < B_) {
    int* lab  = reinterpret_cast<int*>(smem);            // 7200B
    int* lab2 = reinterpret_cast<int*>(smem + 7200);     // 7200B
    u64* best = reinterpret_cast<u64*>(smem + 14400);    // 14400B (8-aligned)
    int* wsum = reinterpret_cast<int*>(smem + 28800);    // [4]
    int* stot = reinterpret_cast<int*>(smem + 28816);
    int* schg = reinterpret_cast<int*>(smem + 28820);
    const int b = bid;
    const int S = sel_cnt[b];
    const int nw = (S + 63) >> 6;
    const u64* arow0 = adj + (size_t)b * Q_ * WPR;

    // fast pass (== iteration 0 of min-label propagation from identity)
    if (t == 0) *schg = 0;
    __syncthreads();
    for (int s = t; s < S; s += 256) {
      u32 m = rowmin[b * QPAD + s];
      u32 v = ((u32)s < m) ? (u32)s : m;
      lab[s] = (int)v;
      if (v != (u32)s) *schg = 1;           // benign race
    }
    __syncthreads();

    if (*schg) {                            // full verified bitmask fallback
      for (int iter = 0; iter < Q_ + 2; ++iter) {
        if (t == 0) *schg = 0;
        __syncthreads();
        for (int s = t; s < S; s += 256) {
          int m = lab[s];
          const u64* row = arow0 + (size_t)s * WPR;
          for (int w = 0; w < nw; ++w) {
            u64 msk = row[w];
            while (msk) {
              int j = (w << 6) + __builtin_ctzll(msk);
              int lj = lab[j];
              m = (lj < m) ? lj : m;
              msk &= msk - 1;
            }
          }
          lab2[s] = m;
          if (m != lab[s]) *schg = 1;
        }
        __syncthreads();
        int ch = *schg;
        for (int s = t; s < S; s += 256) lab[s] = lab2[s];
        __syncthreads();
        if (!ch) break;
      }
    }

    for (int s = t; s < S; s += 256) best[s] = 0ull;
    __syncthreads();
    const float* scb = scores + b * Q_;
    const int* sidx = sel_idx + b * Q_;
    for (int s = t; s < S; s += 256) {
      int orig = sidx[s];
      float sc = scb[orig];
      u64 key = ((u64)__float_as_uint(sc) << 32) | (u32)(~(u32)orig);
      atomicMax(&best[lab[s]], key);
    }
    __syncthreads();

    int f[8]; int cnt = 0;
    #pragma unroll
    for (int e = 0; e < 8; ++e) {
      int s = t * 8 + e;
      int fl = (s < S && lab[s] == s) ? 1 : 0;
      f[e] = fl; cnt += fl;
    }
    int incl = cnt;
    #pragma unroll
    for (int d = 1; d < 64; d <<= 1) {
      int v = __shfl_up(incl, d, 64);
      if (lane >= d) incl += v;
    }
    if (lane == 63) wsum[wid] = incl;
    __syncthreads();
    if (t == 0) {
      int acc = 0;
      #pragma unroll
      for (int i = 0; i < 4; ++i) { int v = wsum[i]; wsum[i] = acc; acc += v; }
      *stot = acc;
    }
    __syncthreads();
    int excl = wsum[wid] + incl - cnt;
    #pragma unroll
    for (int e = 0; e < 8; ++e) {
      if (f[e]) {
        int s = t * 8 + e;
        u64 key = best[s];
        best_idx[b * Q_ + excl] = (int)(~(u32)key);
        best_sc[b * Q_ + excl] = __uint_as_float((u32)(key >> 32));
        excl++;
      }
    }
    if (t == 0) nroots[b] = *stot;
  }
  grid.sync();

  // ================= Phase 5: write ALL outputs ============================
  for (int task = bid; task < B_ * (Q_ / 4); task += (int)gridDim.x) {
    int b = task / (Q_ / 4);
    int g = task - b * (Q_ / 4);
    int p = g * 4 + wid;
    int n = nroots[b];
    float* orow = out_sig + ((size_t)b * Q_ + p) * C_;
    if (p < n) {
      int row = best_idx[b * Q_ + p];
      float4 v = *reinterpret_cast<const float4*>(sig + ((size_t)b * Q_ + row) * C_ + lane * 4);
      *reinterpret_cast<float4*>(orow + lane * 4) = v;
      if (lane == 0) {
        out_mask[b * Q_ + p] = 1.0f;
        out_scores[b * Q_ + p] = best_sc[b * Q_ + p];
      }
    } else {
      *reinterpret_cast<float4*>(orow + lane * 4) = make_float4(0.f, 0.f, 0.f, 0.f);
      if (lane == 0) {
        out_mask[b * Q_ + p] = 0.0f;
        out_scores[b * Q_ + p] = 0.0f;
      }
    }
  }
}

// ============================================================================
// Verified round-9 fallback chain (verbatim)
// ============================================================================
__global__ __launch_bounds__(256)
void k_compact(const float* __restrict__ logits, float* __restrict__ scores,
               int* __restrict__ sel_idx, int* __restrict__ sel_cnt) {
  int b = blockIdx.x, t = threadIdx.x;
  int lane = t & 63, wid = t >> 6;
  __shared__ int wsum[4];
  __shared__ int s_tot;
  __shared__ u64 kw[4];
  const float* lgb = logits + b * Q_;
  float* scb = scores + b * Q_;

  int f[8]; int cnt = 0; u64 mk = 0;
  #pragma unroll
  for (int e = 0; e < 8; ++e) {
    int q = t * 8 + e;
    int fl = 0;
    if (q < Q_) {
      float sc = 1.0f / (1.0f + expf(-lgb[q]));
      scb[q] = sc;
      fl = (sc >= 0.5f) ? 1 : 0;
      u64 key = ((u64)__float_as_uint(sc) << 32) | (u32)(~(u32)q);
      mk = (mk > key) ? mk : key;
    }
    f[e] = fl; cnt += fl;
  }
  int incl = cnt;
  #pragma unroll
  for (int d = 1; d < 64; d <<= 1) {
    int v = __shfl_up(incl, d, 64);
    if (lane >= d) incl += v;
  }
  if (lane == 63) wsum[wid] = incl;
  __syncthreads();
  if (t == 0) {
    int acc = 0;
    #pragma unroll
    for (int i = 0; i < 4; ++i) { int v = wsum[i]; wsum[i] = acc; acc += v; }
    s_tot = acc;
  }
  __syncthreads();
  int excl = wsum[wid] + incl - cnt;
  int total = s_tot;

  if (total > 0) {
    #pragma unroll
    for (int e = 0; e < 8; ++e) {
      if (f[e]) { sel_idx[b * Q_ + excl] = t * 8 + e; excl++; }
    }
    if (t == 0) sel_cnt[b] = total;
  } else {
    u64 r = mk;
    #pragma unroll
    for (int d = 1; d < 64; d <<= 1) {
      u64 o = __shfl_xor(r, d, 64);
      r = (o > r) ? o : r;
    }
    if (lane == 0) kw[wid] = r;
    __syncthreads();
    if (t == 0) {
      u64 m2 = kw[0];
      #pragma unroll
      for (int i = 1; i < 4; ++i) m2 = (kw[i] > m2) ? kw[i] : m2;
      sel_idx[b * Q_] = (int)(~(u32)m2);
      sel_cnt[b] = 1;
    }
  }
}

__global__ __launch_bounds__(256)
void k_prep(const float* __restrict__ sig, const int* __restrict__ sel_idx,
            const int* __restrict__ sel_cnt, unsigned short* __restrict__ nsig,
            u32* __restrict__ rowmin) {
  int b = blockIdx.y;
  int p = blockIdx.x * 4 + (threadIdx.x >> 6);
  int lane = threadIdx.x & 63;
  int S = sel_cnt[b];
  int Spad = (S + 63) & ~63;
  if (p >= Spad) return;
  if (lane == 0) rowmin[b * QPAD + p] = 0xFFFFFFFFu;
  unsigned short* dst = nsig + ((size_t)b * QPAD + p) * C_;
  if (p >= S) {
    *reinterpret_cast<uint2*>(dst + lane * 4) = make_uint2(0u, 0u);
    return;
  }
  int row = sel_idx[b * Q_ + p];
  const float* src = sig + ((size_t)b * Q_ + row) * C_;
  float4 v = *reinterpret_cast<const float4*>(src + lane * 4);
  float ss = v.x * v.x + v.y * v.y + v.z * v.z + v.w * v.w;
  #pragma unroll
  for (int m = 32; m; m >>= 1) ss += __shfl_xor(ss, m, 64);
  float inv = 1.0f / fmaxf(sqrtf(ss), 1e-12f);
  __hip_bfloat16 h0 = __float2bfloat16(v.x * inv);
  __hip_bfloat16 h1 = __float2bfloat16(v.y * inv);
  __hip_bfloat16 h2 = __float2bfloat16(v.z * inv);
  __hip_bfloat16 h3 = __float2bfloat16(v.w * inv);
  unsigned short u0, u1, u2, u3;
  __builtin_memcpy(&u0, &h0, 2); __builtin_memcpy(&u1, &h1, 2);
  __builtin_memcpy(&u2, &h2, 2); __builtin_memcpy(&u3, &h3, 2);
  uint2 wv;
  wv.x = (u32)u0 | ((u32)u1 << 16);
  wv.y = (u32)u2 | ((u32)u3 << 16);
  *reinterpret_cast<uint2*>(dst + lane * 4) = wv;
}

__global__ __launch_bounds__(256)
void k_sim(const unsigned short* __restrict__ nsig, const int* __restrict__ sel_cnt,
           u64* __restrict__ adj, u32* __restrict__ rowmin) {
  int lin = blockIdx.x;
  int b = lin & 15;
  int tile = lin >> 4;
  int tib = tile / TBK, tjb = tile - tib * TBK;
  if (tib > tjb) return;
  int S = sel_cnt[b];
  if (tjb * 128 >= S || tib * 128 >= S) return;
  const bool diag = (tib == tjb);

  __shared__ uint4 Alds[2048];
  __shared__ uint4 Blds[2048];
  __shared__ u64 adjtile[4][64];

  const int t = threadIdx.x;
  const int wv = t >> 6, lane = t & 63;
  const int lr = lane & 15, lg = lane >> 4;

  const int i1 = tib * 128 + (wv >> 1) * 64;
  const int j1 = tjb * 128 + (wv & 1) * 64;
  const bool live = (i1 < S) && (j1 < S);

  const char* gbase = (const char*)(nsig + (size_t)b * QPAD * C_);
  const char* arow = gbase + (size_t)tib * 128 * 512;
  const char* brow = gbase + (size_t)tjb * 128 * 512;

  f32x4 acc[4][4];
  #pragma unroll
  for (int rs = 0; rs < 4; ++rs)
    #pragma unroll
    for (int cg = 0; cg < 4; ++cg) acc[rs][cg] = (f32x4){0.f, 0.f, 0.f, 0.f};

  const int ra0 = (wv >> 1) * 64;
  const int rb0 = (wv & 1) * 64;
  const char* Bbase = reinterpret_cast<const char*>(diag ? Alds : Blds);

  for (int kh = 0; kh < 2; ++kh) {
    #pragma unroll
    for (int it = 0; it < 8; ++it) {
      int o = it * 4096 + t * 16;
      int r = o >> 8;
      int w = o & 255;
      int sw = o ^ ((r & 7) << 4);
      uint4 va = *reinterpret_cast<const uint4*>(arow + (size_t)r * 512 + kh * 256 + w);
      Alds[sw >> 4] = va;
      if (!diag) {
        uint4 vb = *reinterpret_cast<const uint4*>(brow + (size_t)r * 512 + kh * 256 + w);
        Blds[sw >> 4] = vb;
      }
    }
    __syncthreads();
    if (live) {
      #pragma unroll
      for (int ks = 0; ks < 4; ++ks) {
        bf16x8 af[4], bf[4];
        #pragma unroll
        for (int rs = 0; rs < 4; ++rs) {
          int r = ra0 + rs * 16 + lr;
          int byte = r * 256 + ((ks * 64 + lg * 16) ^ ((r & 7) << 4));
          af[rs] = *reinterpret_cast<const bf16x8*>(
              reinterpret_cast<const char*>(Alds) + byte);
        }
        #pragma unroll
        for (int cg = 0; cg < 4; ++cg) {
          int r = rb0 + cg * 16 + lr;
          int byte = r * 256 + ((ks * 64 + lg * 16) ^ ((r & 7) << 4));
          bf[cg] = *reinterpret_cast<const bf16x8*>(Bbase + byte);
        }
        #pragma unroll
        for (int rs = 0; rs < 4; ++rs)
          #pragma unroll
          for (int cg = 0; cg < 4; ++cg)
            acc[rs][cg] = __builtin_amdgcn_mfma_f32_16x16x32_bf16(
                af[rs], bf[cg], acc[rs][cg], 0, 0, 0);
      }
    }
    __syncthreads();
  }

  if (!live) return;
  adjtile[wv][lane] = 0ull;
  #pragma unroll
  for (int rs = 0; rs < 4; ++rs) {
    #pragma unroll
    for (int j = 0; j < 4; ++j) {
      u64 bits = 0ull;
      if (acc[rs][0][j] >= 0.8f) bits |= 1ull << (0  + lr);
      if (acc[rs][1][j] >= 0.8f) bits |= 1ull << (16 + lr);
      if (acc[rs][2][j] >= 0.8f) bits |= 1ull << (32 + lr);
      if (acc[rs][3][j] >= 0.8f) bits |= 1ull << (48 + lr);
      if (bits) atomicOr(&adjtile[wv][rs * 16 + lg * 4 + j], bits);
    }
  }
  int gi = i1 + lane;
  u64 word = adjtile[wv][lane];
  if (gi < S) {
    adj[((size_t)b * Q_ + gi) * WPR + (j1 >> 6)] = word;
    if (word) atomicMin(&rowmin[b * QPAD + gi], (u32)(j1 + __builtin_ctzll(word)));
  }
  if (!diag) {
    u64 tw = 0ull;
    for (int i = 0; i < 64; ++i)
      tw |= ((adjtile[wv][i] >> lane) & 1ull) << i;
    int gj = j1 + lane;
    if (gj < S) {
      adj[((size_t)b * Q_ + gj) * WPR + (i1 >> 6)] = tw;
      if (tw) atomicMin(&rowmin[b * QPAD + gj], (u32)(i1 + __builtin_ctzll(tw)));
    }
  }
}

__global__ __launch_bounds__(1024)
void k_cc(const float* __restrict__ scores, const int* __restrict__ sel_idx,
          const int* __restrict__ sel_cnt, const u64* __restrict__ adj,
          const u32* __restrict__ rowmin,
          int* __restrict__ best_idx, float* __restrict__ best_sc,
          int* __restrict__ nroots) {
  int b = blockIdx.x, t = threadIdx.x;
  int lane = t & 63, wid = t >> 6;
  __shared__ int lab[Q_];
  __shared__ int lab2[Q_];
  __shared__ u64 best[Q_];
  __shared__ int wsum[16];
  __shared__ int s_tot;
  __shared__ int s_changed;

  int S = sel_cnt[b];
  int nw = (S + 63) >> 6;
  const u64* arow0 = adj + (size_t)b * Q_ * WPR;

  if (t == 0) s_changed = 0;
  __syncthreads();
  for (int s = t; s < S; s += 1024) {
    u32 m = rowmin[b * QPAD + s];
    u32 v = ((u32)s < m) ? (u32)s : m;
    lab[s] = (int)v;
    if (v != (u32)s) s_changed = 1;
  }
  __syncthreads();

  if (s_changed) {
    for (int iter = 0; iter < Q_ + 2; ++iter) {
      if (t == 0) s_changed = 0;
      __syncthreads();
      for (int s = t; s < S; s += 1024) {
        int m = lab[s];
        const u64* row = arow0 + (size_t)s * WPR;
        for (int w = 0; w < nw; ++w) {
          u64 msk = row[w];
          while (msk) {
            int j = (w << 6) + __builtin_ctzll(msk);
            int lj = lab[j];
            m = (lj < m) ? lj : m;
            msk &= msk - 1;
          }
        }
        lab2[s] = m;
        if (m != lab[s]) s_changed = 1;
      }
      __syncthreads();
      int ch = s_changed;
      for (int s = t; s < S; s += 1024) lab[s] = lab2[s];
      __syncthreads();
      if (!ch) break;
    }
  }

  for (int s = t; s < S; s += 1024) best[s] = 0ull;
  __syncthreads();
  const float* scb = scores + b * Q_;
  const int* sidx = sel_idx + b * Q_;
  for (int s = t; s < S; s += 1024) {
    int orig = sidx[s];
    float sc = scb[orig];
    u64 key = ((u64)__float_as_uint(sc) << 32) | (u32)(~(u32)orig);
    atomicMax(&best[lab[s]], key);
  }
  __syncthreads();

  int f[2]; int cnt = 0;
  #pragma unroll
  for (int e = 0; e < 2; ++e) {
    int s = t * 2 + e;
    int fl = (s < S && lab[s] == s) ? 1 : 0;
    f[e] = fl; cnt += fl;
  }
  int incl = cnt;
  #pragma unroll
  for (int d = 1; d < 64; d <<= 1) {
    int v = __shfl_up(incl, d, 64);
    if (lane >= d) incl += v;
  }
  if (lane == 63) wsum[wid] = incl;
  __syncthreads();
  if (t == 0) {
    int acc = 0;
    #pragma unroll
    for (int i = 0; i < 16; ++i) { int v = wsum[i]; wsum[i] = acc; acc += v; }
    s_tot = acc;
  }
  __syncthreads();
  int excl = wsum[wid] + incl - cnt;
  #pragma unroll
  for (int e = 0; e < 2; ++e) {
    if (f[e]) {
      int s = t * 2 + e;
      u64 key = best[s];
      best_idx[b * Q_ + excl] = (int)(~(u32)key);
      best_sc[b * Q_ + excl] = __uint_as_float((u32)(key >> 32));
      excl++;
    }
  }
  if (t == 0) nroots[b] = s_tot;
}

__global__ __launch_bounds__(256)
void k_gather(const float* __restrict__ sig, const int* __restrict__ best_idx,
              const float* __restrict__ best_sc, const int* __restrict__ nroots,
              float* __restrict__ out_sig, float* __restrict__ out_mask,
              float* __restrict__ out_scores) {
  int b = blockIdx.y;
  int p = blockIdx.x * 4 + (threadIdx.x >> 6);
  int lane = threadIdx.x & 63;
  if (p >= Q_) return;
  int n = nroots[b];
  float* orow = out_sig + ((size_t)b * Q_ + p) * C_;
  if (p < n) {
    int row = best_idx[b * Q_ + p];
    float4 v = *reinterpret_cast<const float4*>(sig + ((size_t)b * Q_ + row) * C_ + lane * 4);
    *reinterpret_cast<float4*>(orow + lane * 4) = v;
    if (lane == 0) {
      out_mask[b * Q_ + p] = 1.0f;
      out_scores[b * Q_ + p] = best_sc[b * Q_ + p];
    }
  } else {
    *reinterpret_cast<float4*>(orow + lane * 4) = make_float4(0.f, 0.f, 0.f, 0.f);
    if (lane == 0) {
      out_mask[b * Q_ + p] = 0.0f;
      out_scores[b * Q_ + p] = 0.0f;
    }
  }
}

extern "C" void kernel_launch(void* const* d_in, const int* in_sizes, int n_in,
                              void* d_out, int out_size, void* d_ws, size_t ws_size,
                              hipStream_t stream) {
  const float* p0 = (const float*)d_in[0];
  const float* p1 = (const float*)d_in[1];
  const float* sig;  const float* logits;
  if (in_sizes[0] == B_ * Q_ * C_) { sig = p0; logits = p1; }
  else                             { sig = p1; logits = p0; }

  float* out = (float*)d_out;
  float* out_mask   = out + OUT_SIG_ELEMS;
  float* out_scores = out + OUT_SIG_ELEMS + B_ * Q_;

  char* ws = (char*)d_ws;
  float* scores  = (float*)ws;  ws += B_ * Q_ * 4;
  int* sel_idx   = (int*)ws;    ws += B_ * Q_ * 4;
  int* best_idx  = (int*)ws;    ws += B_ * Q_ * 4;
  float* best_sc = (float*)ws;  ws += B_ * Q_ * 4;
  int* sel_cnt   = (int*)ws;    ws += 256;
  int* nroots    = (int*)ws;    ws += 256;

  // scratch in d_out: adj [0,6.4MiB), nsig [8MiB,22.5MiB), rowmin [26MiB..).
  // All fully (re)initialized before use each launch; final phase overwrites
  // all of d_out with outputs.
  u64* adj = (u64*)d_out;
  unsigned short* nsig = (unsigned short*)((char*)d_out + (size_t)(8u << 20));
  u32* rowmin = (u32*)((char*)d_out + (size_t)(26u << 20));

  // ---- try the fused cooperative kernel; fall back to the verified chain --
  void* args[] = {
    (void*)&sig, (void*)&logits, (void*)&out, (void*)&out_mask,
    (void*)&out_scores, (void*)&scores, (void*)&sel_idx, (void*)&best_idx,
    (void*)&best_sc, (void*)&sel_cnt, (void*)&nroots, (void*)&adj,
    (void*)&nsig, (void*)&rowmin
  };
  hipError_t ce = hipLaunchCooperativeKernel((const void*)k_fused, dim3(512),
                                             dim3(256), args, 0, stream);
  if (ce != hipSuccess) {
    (void)hipGetLastError();               // clear sticky error
    ce = hipLaunchCooperativeKernel((const void*)k_fused, dim3(256),
                                    dim3(256), args, 0, stream);
  }
  if (ce != hipSuccess) {
    (void)hipGetLastError();               // clear sticky error, run chain
    k_compact<<<B_, 256, 0, stream>>>(logits, scores, sel_idx, sel_cnt);
    dim3 gp(QPAD / 4, B_);
    k_prep<<<gp, 256, 0, stream>>>(sig, sel_idx, sel_cnt, nsig, rowmin);
    k_sim<<<B_ * TBK * TBK, 256, 0, stream>>>(nsig, sel_cnt, adj, rowmin);
    k_cc<<<B_, 1024, 0, stream>>>(scores, sel_idx, sel_cnt, adj, rowmin,
                                  best_idx, best_sc, nroots);
    dim3 gg(Q_ / 4, B_);
    k_gather<<<gg, 256, 0, stream>>>(sig, best_idx, best_sc, nroots,
                                     out, out_mask, out_scores);
  }
}

// Round 12
// 99.806 us; speedup vs baseline: 2.9601x; 2.9601x over previous
//
#include <hip/hip_runtime.h>
#include <hip/hip_bf16.h>
#include <stdint.h>

#define B_ 16
#define Q_ 1800
#define C_ 256
#define WPR 29            // u64 words per adjacency row = ceil(1800/64)
#define QPAD 1856         // padded compacted-row capacity
#define TBK 15            // 128-wide tiles per dim: 15*128 = 1920 >= QPAD
#define NTRI 120          // triangular tile count = TBK*(TBK+1)/2
#define OUT_SIG_ELEMS (B_*Q_*C_)

typedef unsigned long long u64;
typedef unsigned int u32;
typedef __attribute__((ext_vector_type(8))) short bf16x8;   // 8 bf16 (4 VGPRs)
typedef __attribute__((ext_vector_type(4))) float f32x4;    // 4 fp32 acc

// ---------------- K1: fused selection + normalize -> compacted bf16 --------
// Every block redundantly computes the batch's selection scan (~7KB read +
// shuffle scan, ~1us, fully parallel) -> no separate compact kernel/launch.
// Block g==0 additionally publishes sel_idx/sel_cnt for later kernels.
__global__ __launch_bounds__(256)
void k_prep2(const float* __restrict__ sig, const float* __restrict__ logits,
             int* __restrict__ sel_idx, int* __restrict__ sel_cnt,
             unsigned short* __restrict__ nsig, u32* __restrict__ rowmin) {
  const int b = blockIdx.y, g = blockIdx.x;
  const int t = threadIdx.x, lane = t & 63, wid = t >> 6;
  __shared__ int wsum[4];
  __shared__ u64 kw[4];
  __shared__ int s_tot;
  __shared__ int slot[4];

  const float* lgb = logits + b * Q_;
  int f[8]; int cnt = 0; u64 mk = 0;
  #pragma unroll
  for (int e = 0; e < 8; ++e) {
    int q = t * 8 + e; int fl = 0;
    if (q < Q_) {
      float sc = 1.0f / (1.0f + expf(-lgb[q]));
      fl = (sc >= 0.5f) ? 1 : 0;
      u64 key = ((u64)__float_as_uint(sc) << 32) | (u32)(~(u32)q); // max score, min idx
      mk = (mk > key) ? mk : key;
    }
    f[e] = fl; cnt += fl;
  }
  int incl = cnt;
  #pragma unroll
  for (int d = 1; d < 64; d <<= 1) { int v = __shfl_up(incl, d, 64); if (lane >= d) incl += v; }
  if (lane == 63) wsum[wid] = incl;
  __syncthreads();
  if (t == 0) {
    int acc = 0;
    #pragma unroll
    for (int i = 0; i < 4; ++i) { int v = wsum[i]; wsum[i] = acc; acc += v; }
    s_tot = acc;
  }
  __syncthreads();
  int excl0 = wsum[wid] + incl - cnt;
  int S = s_tot;
  int fbq = -1;
  if (S == 0) {                              // fallback: argmax-score query
    u64 r = mk;
    #pragma unroll
    for (int d = 1; d < 64; d <<= 1) { u64 o = __shfl_xor(r, d, 64); r = (o > r) ? o : r; }
    if (lane == 0) kw[wid] = r;
    __syncthreads();
    u64 m2 = kw[0];
    #pragma unroll
    for (int i = 1; i < 4; ++i) m2 = (kw[i] > m2) ? kw[i] : m2;
    fbq = (int)(~(u32)m2);
    S = 1;
  }
  if (g == 0 && t == 0) sel_cnt[b] = S;

  int Spad = (S + 63) & ~63;
  if (g * 4 >= Spad) return;                 // block-uniform

  if (t < 4) slot[t] = -1;
  __syncthreads();
  if (fbq >= 0) {
    if (g == 0 && t == 0) { slot[0] = fbq; sel_idx[b * Q_] = fbq; }
  } else {
    int ex = excl0;
    #pragma unroll
    for (int e = 0; e < 8; ++e) {
      if (f[e]) {
        int q = t * 8 + e;
        if (g == 0) sel_idx[b * Q_ + ex] = q;
        if (ex >= g * 4 && ex < g * 4 + 4) slot[ex - g * 4] = q;
        ex++;
      }
    }
  }
  __syncthreads();

  int p = g * 4 + wid;
  if (p >= Spad) return;                     // wave-level; no barriers after
  if (lane == 0) rowmin[b * QPAD + p] = 0xFFFFFFFFu;
  unsigned short* dst = nsig + ((size_t)b * QPAD + p) * C_;
  if (p >= S) {                              // zero-pad row
    *reinterpret_cast<uint2*>(dst + lane * 4) = make_uint2(0u, 0u);
    return;
  }
  int row = slot[wid];
  const float* src = sig + ((size_t)b * Q_ + row) * C_;
  float4 v = *reinterpret_cast<const float4*>(src + lane * 4);
  float ss = v.x * v.x + v.y * v.y + v.z * v.z + v.w * v.w;
  #pragma unroll
  for (int m = 32; m; m >>= 1) ss += __shfl_xor(ss, m, 64);
  float inv = 1.0f / fmaxf(sqrtf(ss), 1e-12f);
  __hip_bfloat16 h0 = __float2bfloat16(v.x * inv);
  __hip_bfloat16 h1 = __float2bfloat16(v.y * inv);
  __hip_bfloat16 h2 = __float2bfloat16(v.z * inv);
  __hip_bfloat16 h3 = __float2bfloat16(v.w * inv);
  unsigned short u0, u1, u2, u3;
  __builtin_memcpy(&u0, &h0, 2); __builtin_memcpy(&u1, &h1, 2);
  __builtin_memcpy(&u2, &h2, 2); __builtin_memcpy(&u3, &h3, 2);
  uint2 wv;
  wv.x = (u32)u0 | ((u32)u1 << 16);
  wv.y = (u32)u2 | ((u32)u3 << 16);
  *reinterpret_cast<uint2*>(dst + lane * 4) = wv;
}

// ---------------- K2: LDS-staged MFMA cosine-sim, triangular ---------------
// Round-9 verified body; triangular enumeration (r11-verified), grid B_*NTRI,
// batch = lin & 15 -> XCD pin (lin%8 == b%8).
__global__ __launch_bounds__(256)
void k_sim(const unsigned short* __restrict__ nsig, const int* __restrict__ sel_cnt,
           u64* __restrict__ adj, u32* __restrict__ rowmin) {
  int lin = blockIdx.x;
  int b = lin & 15;
  int u = lin >> 4, tib = 0;
  while (u >= TBK - tib) { u -= TBK - tib; ++tib; }
  int tjb = tib + u;                          // tib <= tjb < TBK
  int S = sel_cnt[b];
  if (tjb * 128 >= S) return;                 // implies tib*128 < S
  const bool diag = (tib == tjb);

  __shared__ uint4 Alds[2048];
  __shared__ uint4 Blds[2048];
  __shared__ u64 adjtile[4][64];

  const int t = threadIdx.x;
  const int wv = t >> 6, lane = t & 63;
  const int lr = lane & 15, lg = lane >> 4;

  const int i1 = tib * 128 + (wv >> 1) * 64;
  const int j1 = tjb * 128 + (wv & 1) * 64;
  const bool live = (i1 < S) && (j1 < S);

  const char* gbase = (const char*)(nsig + (size_t)b * QPAD * C_);
  const char* arow = gbase + (size_t)tib * 128 * 512;
  const char* brow = gbase + (size_t)tjb * 128 * 512;

  f32x4 acc[4][4];
  #pragma unroll
  for (int rs = 0; rs < 4; ++rs)
    #pragma unroll
    for (int cg = 0; cg < 4; ++cg) acc[rs][cg] = (f32x4){0.f, 0.f, 0.f, 0.f};

  const int ra0 = (wv >> 1) * 64;
  const int rb0 = (wv & 1) * 64;
  const char* Bbase = reinterpret_cast<const char*>(diag ? Alds : Blds);

  for (int kh = 0; kh < 2; ++kh) {
    #pragma unroll
    for (int it = 0; it < 8; ++it) {
      int o = it * 4096 + t * 16;
      int r = o >> 8;
      int w = o & 255;
      int sw = o ^ ((r & 7) << 4);            // swizzled LDS byte offset
      uint4 va = *reinterpret_cast<const uint4*>(arow + (size_t)r * 512 + kh * 256 + w);
      Alds[sw >> 4] = va;
      if (!diag) {
        uint4 vb = *reinterpret_cast<const uint4*>(brow + (size_t)r * 512 + kh * 256 + w);
        Blds[sw >> 4] = vb;
      }
    }
    __syncthreads();
    if (live) {
      #pragma unroll
      for (int ks = 0; ks < 4; ++ks) {
        bf16x8 af[4], bf[4];
        #pragma unroll
        for (int rs = 0; rs < 4; ++rs) {
          int r = ra0 + rs * 16 + lr;
          int byte = r * 256 + ((ks * 64 + lg * 16) ^ ((r & 7) << 4));
          af[rs] = *reinterpret_cast<const bf16x8*>(
              reinterpret_cast<const char*>(Alds) + byte);
        }
        #pragma unroll
        for (int cg = 0; cg < 4; ++cg) {
          int r = rb0 + cg * 16 + lr;
          int byte = r * 256 + ((ks * 64 + lg * 16) ^ ((r & 7) << 4));
          bf[cg] = *reinterpret_cast<const bf16x8*>(Bbase + byte);
        }
        #pragma unroll
        for (int rs = 0; rs < 4; ++rs)
          #pragma unroll
          for (int cg = 0; cg < 4; ++cg)
            acc[rs][cg] = __builtin_amdgcn_mfma_f32_16x16x32_bf16(
                af[rs], bf[cg], acc[rs][cg], 0, 0, 0);
      }
    }
    __syncthreads();
  }

  if (!live) return;
  adjtile[wv][lane] = 0ull;                   // wave-private strip
  #pragma unroll
  for (int rs = 0; rs < 4; ++rs) {
    #pragma unroll
    for (int j = 0; j < 4; ++j) {
      u64 bits = 0ull;
      if (acc[rs][0][j] >= 0.8f) bits |= 1ull << (0  + lr);
      if (acc[rs][1][j] >= 0.8f) bits |= 1ull << (16 + lr);
      if (acc[rs][2][j] >= 0.8f) bits |= 1ull << (32 + lr);
      if (acc[rs][3][j] >= 0.8f) bits |= 1ull << (48 + lr);
      if (bits) atomicOr(&adjtile[wv][rs * 16 + lg * 4 + j], bits);
    }
  }
  int gi = i1 + lane;
  u64 word = adjtile[wv][lane];
  if (gi < S) {
    adj[((size_t)b * Q_ + gi) * WPR + (j1 >> 6)] = word;
    if (word) atomicMin(&rowmin[b * QPAD + gi], (u32)(j1 + __builtin_ctzll(word)));
  }
  if (!diag) {                                // mirrored word via bit-transpose
    u64 tw = 0ull;
    for (int i = 0; i < 64; ++i)
      tw |= ((adjtile[wv][i] >> lane) & 1ull) << i;
    int gj = j1 + lane;
    if (gj < S) {
      adj[((size_t)b * Q_ + gj) * WPR + (i1 >> 6)] = tw;
      if (tw) atomicMin(&rowmin[b * QPAD + gj], (u32)(i1 + __builtin_ctzll(tw)));
    }
  }
}

// ---------------- K3 (big-ws path): fused CC + gather ----------------------
// Each block redundantly recomputes selection + rowmin-fast-path CC + root
// scan (~2us, parallel), then writes its 4 output rows. rowmin/adj MUST live
// in d_ws: output writes to d_out race with other blocks' CC reads otherwise.
__global__ __launch_bounds__(256)
void k_ccgather(const float* __restrict__ sig, const float* __restrict__ logits,
                const u32* __restrict__ rowmin, const u64* __restrict__ adj,
                float* __restrict__ out_sig, float* __restrict__ out_mask,
                float* __restrict__ out_scores) {
  const int b = blockIdx.y, g = blockIdx.x;   // g in [0, Q_/4)
  const int t = threadIdx.x, lane = t & 63, wid = t >> 6;
  __shared__ int lab[Q_];
  __shared__ int lab2[Q_];
  __shared__ u64 best[Q_];
  __shared__ int wsum[4];
  __shared__ u64 kw[4];
  __shared__ int s_tot;
  __shared__ int s_chg;
  __shared__ int slot[4];

  // ---- selection scan (same as prep2, keeps scores) ----
  const float* lgb = logits + b * Q_;
  int f[8]; float sv[8]; int cnt = 0; u64 mk = 0;
  #pragma unroll
  for (int e = 0; e < 8; ++e) {
    int q = t * 8 + e; int fl = 0; float sc = 0.f;
    if (q < Q_) {
      sc = 1.0f / (1.0f + expf(-lgb[q]));
      fl = (sc >= 0.5f) ? 1 : 0;
      u64 key = ((u64)__float_as_uint(sc) << 32) | (u32)(~(u32)q);
      mk = (mk > key) ? mk : key;
    }
    f[e] = fl; sv[e] = sc; cnt += fl;
  }
  int incl = cnt;
  #pragma unroll
  for (int d = 1; d < 64; d <<= 1) { int v = __shfl_up(incl, d, 64); if (lane >= d) incl += v; }
  if (lane == 63) wsum[wid] = incl;
  if (t == 0) s_chg = 0;
  __syncthreads();
  if (t == 0) {
    int acc = 0;
    #pragma unroll
    for (int i = 0; i < 4; ++i) { int v = wsum[i]; wsum[i] = acc; acc += v; }
    s_tot = acc;
  }
  __syncthreads();
  int excl0 = wsum[wid] + incl - cnt;
  int S = s_tot;
  int fbq = -1;
  if (S == 0) {
    u64 r = mk;
    #pragma unroll
    for (int d = 1; d < 64; d <<= 1) { u64 o = __shfl_xor(r, d, 64); r = (o > r) ? o : r; }
    if (lane == 0) kw[wid] = r;
    __syncthreads();
    u64 m2 = kw[0];
    #pragma unroll
    for (int i = 1; i < 4; ++i) m2 = (kw[i] > m2) ? kw[i] : m2;
    fbq = (int)(~(u32)m2);
    S = 1;
  }

  // ---- lab fast pass from rowmin + best init ----
  for (int s = t; s < S; s += 256) best[s] = 0ull;
  if (fbq >= 0) {
    if (t == 0) lab[0] = 0;
  } else {
    int ex = excl0;
    #pragma unroll
    for (int e = 0; e < 8; ++e) {
      if (f[e]) {
        u32 m = rowmin[b * QPAD + ex];
        u32 v = ((u32)ex < m) ? (u32)ex : m;
        lab[ex] = (int)v;
        if (v != (u32)ex) s_chg = 1;          // benign race
        ex++;
      }
    }
  }
  __syncthreads();

  if (s_chg) {                                // full verified bitmask fallback
    const u64* arow0 = adj + (size_t)b * Q_ * WPR;
    int nw = (S + 63) >> 6;
    for (int iter = 0; iter < Q_ + 2; ++iter) {
      if (t == 0) s_chg = 0;
      __syncthreads();
      for (int s = t; s < S; s += 256) {
        int m = lab[s];
        const u64* row = arow0 + (size_t)s * WPR;
        for (int w = 0; w < nw; ++w) {
          u64 msk = row[w];
          while (msk) {
            int j = (w << 6) + __builtin_ctzll(msk);
            int lj = lab[j];
            m = (lj < m) ? lj : m;
            msk &= msk - 1;
          }
        }
        lab2[s] = m;
        if (m != lab[s]) s_chg = 1;
      }
      __syncthreads();
      int ch = s_chg;
      for (int s = t; s < S; s += 256) lab[s] = lab2[s];
      __syncthreads();
      if (!ch) break;
    }
  }

  // ---- best member per component root ----
  if (fbq >= 0) {
    if (t == 0) {
      float sc = 1.0f / (1.0f + expf(-lgb[fbq]));
      best[0] = ((u64)__float_as_uint(sc) << 32) | (u32)(~(u32)fbq);
    }
  } else {
    int ex = excl0;
    #pragma unroll
    for (int e = 0; e < 8; ++e) {
      if (f[e]) {
        int q = t * 8 + e;
        u64 key = ((u64)__float_as_uint(sv[e]) << 32) | (u32)(~(u32)q);
        atomicMax(&best[lab[ex]], key);
        ex++;
      }
    }
  }
  __syncthreads();

  // ---- root scan; find this block's 4 root slots ----
  int rf[8]; int rcnt = 0;
  #pragma unroll
  for (int e = 0; e < 8; ++e) {
    int s = t * 8 + e;
    int fl = (s < S && lab[s] == s) ? 1 : 0;
    rf[e] = fl; rcnt += fl;
  }
  int rincl = rcnt;
  #pragma unroll
  for (int d = 1; d < 64; d <<= 1) { int v = __shfl_up(rincl, d, 64); if (lane >= d) rincl += v; }
  if (t < 4) slot[t] = -1;
  if (lane == 63) wsum[wid] = rincl;
  __syncthreads();
  if (t == 0) {
    int acc = 0;
    #pragma unroll
    for (int i = 0; i < 4; ++i) { int v = wsum[i]; wsum[i] = acc; acc += v; }
    s_tot = acc;
  }
  __syncthreads();
  int rex = wsum[wid] + rincl - rcnt;
  #pragma unroll
  for (int e = 0; e < 8; ++e) {
    if (rf[e]) {
      if (rex >= g * 4 && rex < g * 4 + 4) slot[rex - g * 4] = t * 8 + e;
      rex++;
    }
  }
  __syncthreads();
  int n = s_tot;

  // ---- write this block's 4 output rows ----
  int p = g * 4 + wid;
  float* orow = out_sig + ((size_t)b * Q_ + p) * C_;
  if (p < n) {
    u64 key = best[slot[wid]];
    int orig = (int)(~(u32)key);
    float4 v = *reinterpret_cast<const float4*>(sig + ((size_t)b * Q_ + orig) * C_ + lane * 4);
    *reinterpret_cast<float4*>(orow + lane * 4) = v;
    if (lane == 0) {
      out_mask[b * Q_ + p] = 1.0f;
      out_scores[b * Q_ + p] = __uint_as_float((u32)(key >> 32));
    }
  } else {
    *reinterpret_cast<float4*>(orow + lane * 4) = make_float4(0.f, 0.f, 0.f, 0.f);
    if (lane == 0) {
      out_mask[b * Q_ + p] = 0.0f;
      out_scores[b * Q_ + p] = 0.0f;
    }
  }
}

// ---------------- Small-ws path: separate CC (round-9, sigmoid inline) -----
__global__ __launch_bounds__(1024)
void k_cc2(const float* __restrict__ logits, const int* __restrict__ sel_idx,
           const int* __restrict__ sel_cnt, const u64* __restrict__ adj,
           const u32* __restrict__ rowmin,
           int* __restrict__ best_idx, float* __restrict__ best_sc,
           int* __restrict__ nroots) {
  int b = blockIdx.x, t = threadIdx.x;
  int lane = t & 63, wid = t >> 6;
  __shared__ int lab[Q_];
  __shared__ int lab2[Q_];
  __shared__ u64 best[Q_];
  __shared__ int wsum[16];
  __shared__ int s_tot;
  __shared__ int s_changed;

  int S = sel_cnt[b];
  int nw = (S + 63) >> 6;
  const u64* arow0 = adj + (size_t)b * Q_ * WPR;

  if (t == 0) s_changed = 0;
  __syncthreads();
  for (int s = t; s < S; s += 1024) {
    u32 m = rowmin[b * QPAD + s];
    u32 v = ((u32)s < m) ? (u32)s : m;
    lab[s] = (int)v;
    if (v != (u32)s) s_changed = 1;
  }
  __syncthreads();

  if (s_changed) {
    for (int iter = 0; iter < Q_ + 2; ++iter) {
      if (t == 0) s_changed = 0;
      __syncthreads();
      for (int s = t; s < S; s += 1024) {
        int m = lab[s];
        const u64* row = arow0 + (size_t)s * WPR;
        for (int w = 0; w < nw; ++w) {
          u64 msk = row[w];
          while (msk) {
            int j = (w << 6) + __builtin_ctzll(msk);
            int lj = lab[j];
            m = (lj < m) ? lj : m;
            msk &= msk - 1;
          }
        }
        lab2[s] = m;
        if (m != lab[s]) s_changed = 1;
      }
      __syncthreads();
      int ch = s_changed;
      for (int s = t; s < S; s += 1024) lab[s] = lab2[s];
      __syncthreads();
      if (!ch) break;
    }
  }

  for (int s = t; s < S; s += 1024) best[s] = 0ull;
  __syncthreads();
  const int* sidx = sel_idx + b * Q_;
  for (int s = t; s < S; s += 1024) {
    int orig = sidx[s];
    float sc = 1.0f / (1.0f + expf(-logits[b * Q_ + orig]));
    u64 key = ((u64)__float_as_uint(sc) << 32) | (u32)(~(u32)orig);
    atomicMax(&best[lab[s]], key);
  }
  __syncthreads();

  int f[2]; int cnt = 0;
  #pragma unroll
  for (int e = 0; e < 2; ++e) {
    int s = t * 2 + e;
    int fl = (s < S && lab[s] == s) ? 1 : 0;
    f[e] = fl; cnt += fl;
  }
  int incl = cnt;
  #pragma unroll
  for (int d = 1; d < 64; d <<= 1) {
    int v = __shfl_up(incl, d, 64);
    if (lane >= d) incl += v;
  }
  if (lane == 63) wsum[wid] = incl;
  __syncthreads();
  if (t == 0) {
    int acc = 0;
    #pragma unroll
    for (int i = 0; i < 16; ++i) { int v = wsum[i]; wsum[i] = acc; acc += v; }
    s_tot = acc;
  }
  __syncthreads();
  int excl = wsum[wid] + incl - cnt;
  #pragma unroll
  for (int e = 0; e < 2; ++e) {
    if (f[e]) {
      int s = t * 2 + e;
      u64 key = best[s];
      best_idx[b * Q_ + excl] = (int)(~(u32)key);
      best_sc[b * Q_ + excl] = __uint_as_float((u32)(key >> 32));
      excl++;
    }
  }
  if (t == 0) nroots[b] = s_tot;
}

__global__ __launch_bounds__(256)
void k_gather(const float* __restrict__ sig, const int* __restrict__ best_idx,
              const float* __restrict__ best_sc, const int* __restrict__ nroots,
              float* __restrict__ out_sig, float* __restrict__ out_mask,
              float* __restrict__ out_scores) {
  int b = blockIdx.y;
  int p = blockIdx.x * 4 + (threadIdx.x >> 6);
  int lane = threadIdx.x & 63;
  if (p >= Q_) return;
  int n = nroots[b];
  float* orow = out_sig + ((size_t)b * Q_ + p) * C_;
  if (p < n) {
    int row = best_idx[b * Q_ + p];
    float4 v = *reinterpret_cast<const float4*>(sig + ((size_t)b * Q_ + row) * C_ + lane * 4);
    *reinterpret_cast<float4*>(orow + lane * 4) = v;
    if (lane == 0) {
      out_mask[b * Q_ + p] = 1.0f;
      out_scores[b * Q_ + p] = best_sc[b * Q_ + p];
    }
  } else {
    *reinterpret_cast<float4*>(orow + lane * 4) = make_float4(0.f, 0.f, 0.f, 0.f);
    if (lane == 0) {
      out_mask[b * Q_ + p] = 0.0f;
      out_scores[b * Q_ + p] = 0.0f;
    }
  }
}

extern "C" void kernel_launch(void* const* d_in, const int* in_sizes, int n_in,
                              void* d_out, int out_size, void* d_ws, size_t ws_size,
                              hipStream_t stream) {
  const float* p0 = (const float*)d_in[0];
  const float* p1 = (const float*)d_in[1];
  const float* sig;  const float* logits;
  if (in_sizes[0] == B_ * Q_ * C_) { sig = p0; logits = p1; }
  else                             { sig = p1; logits = p0; }

  float* out = (float*)d_out;
  float* out_mask   = out + OUT_SIG_ELEMS;
  float* out_scores = out + OUT_SIG_ELEMS + B_ * Q_;

  char* w = (char*)d_ws;
  int* sel_cnt = (int*)w;  w += 256;
  int* sel_idx = (int*)w;  w += B_ * Q_ * 4;

  // nsig always in d_out scratch (dead before outputs are written)
  unsigned short* nsig = (unsigned short*)((char*)d_out + (size_t)(8u << 20));

  const size_t need_big = 256 + (size_t)B_ * Q_ * 4 +
                          (size_t)B_ * QPAD * 4 + (size_t)B_ * Q_ * WPR * 8;
  dim3 gp(QPAD / 4, B_);
  dim3 gg(Q_ / 4, B_);

  if (ws_size >= need_big) {
    // 3-kernel path: rowmin+adj in ws so ccgather's CC reads can't race
    // with output writes to d_out.
    u32* rowmin = (u32*)w;  w += (size_t)B_ * QPAD * 4;   // 8B-aligned offset
    u64* adj    = (u64*)w;

    k_prep2<<<gp, 256, 0, stream>>>(sig, logits, sel_idx, sel_cnt, nsig, rowmin);
    k_sim<<<B_ * NTRI, 256, 0, stream>>>(nsig, sel_cnt, adj, rowmin);
    k_ccgather<<<gg, 256, 0, stream>>>(sig, logits, rowmin, adj,
                                       out, out_mask, out_scores);
  } else {
    // 4-kernel fallback (round-9 layout): adj/rowmin in d_out; cc before gather.
    int* best_idx  = (int*)w;   w += B_ * Q_ * 4;
    float* best_sc = (float*)w; w += B_ * Q_ * 4;
    int* nroots    = (int*)w;   w += 256;
    u64* adj    = (u64*)d_out;
    u32* rowmin = (u32*)((char*)d_out + (size_t)(26u << 20));

    k_prep2<<<gp, 256, 0, stream>>>(sig, logits, sel_idx, sel_cnt, nsig, rowmin);
    k_sim<<<B_ * NTRI, 256, 0, stream>>>(nsig, sel_cnt, adj, rowmin);
    k_cc2<<<B_, 1024, 0, stream>>>(logits, sel_idx, sel_cnt, adj, rowmin,
                                   best_idx, best_sc, nroots);
    k_gather<<<gg, 256, 0, stream>>>(sig, best_idx, best_sc, nroots,
                                     out, out_mask, out_scores);
  }
}